// Round 6
// baseline (426.843 us; speedup 1.0000x reference)
//
#include <hip/hip_runtime.h>

typedef unsigned int uint;
typedef unsigned short ushort;

typedef float f32x4 __attribute__((ext_vector_type(4)));
typedef __bf16 bf16x8 __attribute__((ext_vector_type(8)));

__device__ __forceinline__ float bf2f(uint bits) {
  return __uint_as_float(bits << 16);
}
__device__ __forceinline__ ushort f2bf(float f) {
  uint u = __float_as_uint(f);
  u += 0x7fffu + ((u >> 16) & 1u);   // round-to-nearest-even
  return (ushort)(u >> 16);
}
__device__ __forceinline__ uint pack2(float a, float b) {
  return (uint)f2bf(a) | ((uint)f2bf(b) << 16);
}

// inclusive block scan of per-thread values over 256 threads (ts = 256-slot LDS)
__device__ __forceinline__ void block_scan256(int v, int* ts, int tid) {
  ts[tid] = v;
  __syncthreads();
  for (int off = 1; off < 256; off <<= 1) {
    int t_ = 0;
    if (tid >= off) t_ = ts[tid - off];
    __syncthreads();
    if (tid >= off) ts[tid] += t_;
    __syncthreads();
  }
}

// ---------- dtype probe: bf16-packed vs float32 ----------
__global__ void detect_k(const uint* __restrict__ xu, int* __restrict__ flag) {
  uint u = xu[threadIdx.x];
  uint e = (u >> 7) & 0xFFu;
  unsigned long long m = __ballot(e >= 116u && e <= 130u);
  if (threadIdx.x == 0) flag[0] = (__builtin_popcountll(m) >= 32) ? 1 : 0;
}

// ================= atomic-free CSR build (two-level counting sort) ==========
__global__ __launch_bounds__(256) void part_hist(
    const int* __restrict__ src, const int* __restrict__ dst,
    int* __restrict__ gh_d, int* __restrict__ gh_s,
    int B, int P, int nIter, int E) {
  __shared__ int hd[1024], hs[1024];
  const int tid = threadIdx.x, blk = blockIdx.x;
  for (int i = tid; i < B; i += 256) { hd[i] = 0; hs[i] = 0; }
  __syncthreads();
  int e0 = blk * (nIter << 8);
  for (int i = 0; i < nIter; ++i) {
    int e = e0 + (i << 8) + tid;
    if (e < E) {
      atomicAdd(&hd[dst[e] >> 9], 1);
      atomicAdd(&hs[src[e] >> 9], 1);
    }
  }
  __syncthreads();
  for (int i = tid; i < B; i += 256) {
    gh_d[i * P + blk] = hd[i];
    gh_s[i * P + blk] = hs[i];
  }
}

__global__ __launch_bounds__(256) void part_scan(
    int* __restrict__ gh_d, int* __restrict__ gh_s,
    int* __restrict__ btot, int B, int P) {
  __shared__ int ts[256];
  const int tid = threadIdx.x;
  const int id = blockIdx.x;          // [0,2B)
  int* gh = (id < B) ? gh_d : gh_s;
  const int b = (id < B) ? id : id - B;
  int v0 = (2 * tid < P) ? gh[b * P + 2 * tid] : 0;
  int v1 = (2 * tid + 1 < P) ? gh[b * P + 2 * tid + 1] : 0;
  block_scan256(v0 + v1, ts, tid);
  int excl = (tid > 0) ? ts[tid - 1] : 0;
  if (2 * tid < P) gh[b * P + 2 * tid] = excl;
  if (2 * tid + 1 < P) gh[b * P + 2 * tid + 1] = excl + v0;
  if (tid == 255) btot[id] = ts[255];
}

__global__ void bucket_scan(const int* __restrict__ btot,
                            int* __restrict__ bb_d, int* __restrict__ bb_s, int B) {
  if (threadIdx.x == 0) {
    int run = 0;
    for (int i = 0; i < B; ++i) { bb_d[i] = run; run += btot[i]; }
    bb_d[B] = run;
    run = 0;
    for (int i = 0; i < B; ++i) { bb_s[i] = run; run += btot[B + i]; }
    bb_s[B] = run;
  }
}

// pack: src (17b) | dstlocal (9b) << 17   [requires n <= 131072]
__global__ __launch_bounds__(256) void part_scat(
    const int* __restrict__ src, const int* __restrict__ dst,
    const int* __restrict__ gh_d, const int* __restrict__ gh_s,
    const int* __restrict__ bb_d, const int* __restrict__ bb_s,
    uint* __restrict__ ebuf_d, ushort* __restrict__ ebuf_s,
    int B, int P, int nIter, int E) {
  __shared__ int cd[1024], cs[1024];
  const int tid = threadIdx.x, blk = blockIdx.x;
  for (int i = tid; i < B; i += 256) {
    cd[i] = bb_d[i] + gh_d[i * P + blk];
    cs[i] = bb_s[i] + gh_s[i * P + blk];
  }
  __syncthreads();
  int e0 = blk * (nIter << 8);
  for (int i = 0; i < nIter; ++i) {
    int e = e0 + (i << 8) + tid;
    if (e < E) {
      int s = src[e], d = dst[e];
      int pd = atomicAdd(&cd[d >> 9], 1);
      ebuf_d[pd] = (uint)s | ((uint)(d & 511) << 17);
      int ps = atomicAdd(&cs[s >> 9], 1);
      ebuf_s[ps] = (ushort)(s & 511);
    }
  }
}

// K5: dst side -> row_off/nd/csr. src side -> ns AND the pre-scaled bf16
// feature cast xb[g][:] = bf16(x[g][:] * ns[g])  (rows of this bucket are
// contiguous and bucket-exclusive).
__global__ __launch_bounds__(256) void fine_k(
    const uint* __restrict__ ebuf_d, const ushort* __restrict__ ebuf_s,
    const int* __restrict__ bb_d, const int* __restrict__ bb_s,
    int* __restrict__ row_off, int* __restrict__ csr,
    float* __restrict__ ns, float* __restrict__ nd,
    const void* __restrict__ xp, uint* __restrict__ xb,
    const int* __restrict__ flagp, int do_cast,
    int B, int n, int E) {
  __shared__ int cnt[512];
  __shared__ int off[512];
  __shared__ int ts[256];
  const int tid = threadIdx.x;
  const int id = blockIdx.x;          // [0,2B)
  for (int i = tid; i < 512; i += 256) cnt[i] = 0;
  __syncthreads();
  if (id < B) {
    const int b = id;
    const int lo = bb_d[b], hi = bb_d[b + 1];
    for (int e = lo + tid; e < hi; e += 256)
      atomicAdd(&cnt[(ebuf_d[e] >> 17) & 511], 1);
    __syncthreads();
    int c0 = cnt[2 * tid], c1 = cnt[2 * tid + 1];
    block_scan256(c0 + c1, ts, tid);
    int excl = (tid > 0) ? ts[tid - 1] : 0;
    off[2 * tid] = excl;
    off[2 * tid + 1] = excl + c0;
    __syncthreads();
    for (int i = tid; i < 512; i += 256) {
      int g = b * 512 + i;
      if (g < n) {
        row_off[g] = lo + off[i];
        nd[g] = rsqrtf(fmaxf((float)cnt[i], 1.f));
      }
    }
    if (id == 0 && tid == 0) row_off[n] = E;
    __syncthreads();
    for (int i = tid; i < 512; i += 256) cnt[i] = off[i];  // cnt -> cursor
    __syncthreads();
    for (int e = lo + tid; e < hi; e += 256) {
      uint v = ebuf_d[e];
      int l = (v >> 17) & 511;
      int slot = atomicAdd(&cnt[l], 1);
      csr[lo + slot] = (int)(v & 0x1FFFFu);
    }
  } else {
    const int b = id - B;
    const int lo = bb_s[b], hi = bb_s[b + 1];
    for (int e = lo + tid; e < hi; e += 256)
      atomicAdd(&cnt[ebuf_s[e]], 1);
    __syncthreads();
    for (int i = tid; i < 512; i += 256) {
      int g = b * 512 + i;
      if (g < n) ns[g] = rsqrtf(fmaxf((float)cnt[i], 1.f));
    }
    if (do_cast) {
      const int bf = *flagp;
      const int w = tid >> 6, lane = tid & 63;
      for (int r = w; r < 512; r += 4) {
        int g = b * 512 + r;
        if (g >= n) break;
        float sc = rsqrtf(fmaxf((float)cnt[r], 1.f));
        uint o;
        if (bf) {
          uint v = ((const uint*)xp)[(size_t)g * 64 + lane];
          o = pack2(bf2f(v & 0xffffu) * sc, bf2f(v >> 16) * sc);
        } else {
          float2 v = ((const float2*)xp)[(size_t)g * 64 + lane];
          o = pack2(v.x * sc, v.y * sc);
        }
        xb[(size_t)g * 64 + lane] = o;
      }
    }
  }
}

// ---------- W fragment pre-swizzle (B-operand layout, 16x16x32 bf16) ----------
__global__ void wswz(const void* __restrict__ W1p, const void* __restrict__ W2p,
                     ushort* __restrict__ wf1, ushort* __restrict__ wf2,
                     const int* __restrict__ flagp) {
  int bf = *flagp;
  int tid = blockIdx.x * blockDim.x + threadIdx.x;  // 0..4095
  const void* W = (tid & 2048) ? W2p : W1p;
  ushort* wf = (tid & 2048) ? wf2 : wf1;
  int chunk = tid & 2047;
  int n0 = chunk & 15;
  int quad = (chunk >> 4) & 3;
  int kk = (chunk >> 6) & 3;
  int c = chunk >> 8;
  int col = c * 16 + n0;
#pragma unroll
  for (int j = 0; j < 8; ++j) {
    int idx = (kk * 32 + quad * 8 + j) * 128 + col;
    ushort v = bf ? ((const ushort*)W)[idx] : f2bf(((const float*)W)[idx]);
    wf[chunk * 8 + j] = v;
  }
}

// ---------- fused aggregate + GEMM ----------
// out[d][:] = post( nd[d] * (Sum_{e:dst=d} srcrow[src_e]) @ W + b )
// layer1 (relu_scale=1): post = relu(.) * ns[d], stored bf16 (prescaled y1)
// layer2 (is_final=1):   post = identity, stored f32 (or bf16 if bf inputs)
__global__ __launch_bounds__(256, 4) void aggemm(
    const void* __restrict__ srcdat, const int* __restrict__ row_off,
    const int* __restrict__ csr, const float* __restrict__ nd,
    const float* __restrict__ ns, const ushort* __restrict__ wf,
    const void* __restrict__ bp, void* __restrict__ outp,
    int prescaled, int relu_scale, int is_final,
    const int* __restrict__ flagp, int n) {
  __shared__ __align__(16) ushort Xs[64][136];
  const int tid = threadIdx.x;
  const int w = tid >> 6;        // wave 0..3
  const int lane = tid & 63;
  const int nodebase = blockIdx.x * 64;
  const int bf = *flagp;

  const uint* xu = (const uint*)srcdat;
  const float2* xf = (const float2*)srcdat;

  // phase A: each wave gathers+aggregates 16 node rows into LDS (bf16)
  for (int i = 0; i < 16; ++i) {
    int node = nodebase + w * 16 + i;
    float a0 = 0.f, a1 = 0.f;
    if (node < n) {
      int e = row_off[node], e1 = row_off[node + 1];
      if (prescaled) {
        for (; e + 4 <= e1; e += 4) {
          int s0 = csr[e], s1 = csr[e + 1], s2 = csr[e + 2], s3 = csr[e + 3];
          uint v0 = xu[(size_t)s0 * 64 + lane];
          uint v1 = xu[(size_t)s1 * 64 + lane];
          uint v2 = xu[(size_t)s2 * 64 + lane];
          uint v3 = xu[(size_t)s3 * 64 + lane];
          a0 += (bf2f(v0 & 0xffffu) + bf2f(v1 & 0xffffu)) +
                (bf2f(v2 & 0xffffu) + bf2f(v3 & 0xffffu));
          a1 += (bf2f(v0 >> 16) + bf2f(v1 >> 16)) +
                (bf2f(v2 >> 16) + bf2f(v3 >> 16));
        }
        for (; e < e1; ++e) {
          uint v = xu[(size_t)csr[e] * 64 + lane];
          a0 += bf2f(v & 0xffffu);
          a1 += bf2f(v >> 16);
        }
      } else if (bf) {               // fallback: raw bf16 x, scale per edge
        for (; e < e1; ++e) {
          int s = csr[e];
          float sc = ns[s];
          uint v = xu[(size_t)s * 64 + lane];
          a0 += bf2f(v & 0xffffu) * sc;
          a1 += bf2f(v >> 16) * sc;
        }
      } else {                       // fallback: raw f32 x, scale per edge
        for (; e < e1; ++e) {
          int s = csr[e];
          float sc = ns[s];
          float2 v = xf[(size_t)s * 64 + lane];
          a0 += v.x * sc;
          a1 += v.y * sc;
        }
      }
    }
    *(uint*)&Xs[w * 16 + i][2 * lane] = pack2(a0, a1);
  }
  __syncthreads();

  // phase B: 16x128 @ 128x128 MFMA per wave; W frags read from L2 (32 KB hot)
  const int m = lane & 15;
  const int quad = lane >> 4;
  bf16x8 a[4];
#pragma unroll
  for (int kk = 0; kk < 4; ++kk)
    a[kk] = *(const bf16x8*)&Xs[w * 16 + m][kk * 32 + quad * 8];

  int nodes[4];
  float ndv[4], nsv[4];
#pragma unroll
  for (int reg = 0; reg < 4; ++reg) {
    int node = nodebase + w * 16 + quad * 4 + reg;
    nodes[reg] = node;
    ndv[reg] = (node < n) ? nd[node] : 0.f;
    nsv[reg] = (relu_scale && node < n) ? ns[node] : 1.f;
  }
  const int out32 = is_final && !bf;

#pragma unroll
  for (int c = 0; c < 8; ++c) {
    f32x4 acc = {0.f, 0.f, 0.f, 0.f};
#pragma unroll
    for (int kk = 0; kk < 4; ++kk) {
      bf16x8 b = *(const bf16x8*)&wf[(((c * 4 + kk) * 4 + quad) * 16 + m) * 8];
      acc = __builtin_amdgcn_mfma_f32_16x16x32_bf16(a[kk], b, acc, 0, 0, 0);
    }
    int col = c * 16 + m;
    float bv = bf ? bf2f(((const ushort*)bp)[col]) : ((const float*)bp)[col];
#pragma unroll
    for (int reg = 0; reg < 4; ++reg) {
      if (nodes[reg] < n) {
        float v = acc[reg] * ndv[reg] + bv;
        if (relu_scale) v = fmaxf(v, 0.f) * nsv[reg];
        if (out32)
          ((float*)outp)[(size_t)nodes[reg] * 128 + col] = v;
        else
          ((ushort*)outp)[(size_t)nodes[reg] * 128 + col] = f2bf(v);
      }
    }
  }
}

extern "C" void kernel_launch(void* const* d_in, const int* in_sizes, int n_in,
                              void* d_out, int out_size, void* d_ws, size_t ws_size,
                              hipStream_t stream) {
  int n = in_sizes[0] / 128;   // 100000 nodes
  int E = in_sizes[1];         // 1600000 edges

  const void* feat = d_in[0];
  const int* src = (const int*)d_in[1];
  const int* dst = (const int*)d_in[2];
  const void* W1 = d_in[3];
  const void* b1 = d_in[4];
  const void* W2 = d_in[5];
  const void* b2 = d_in[6];

  // sort geometry
  const int B = (n + 511) >> 9;          // 196 coarse buckets for n=100k
  int chunk = 4096;
  int P = (E + chunk - 1) / chunk;
  if (P > 512) {
    chunk = (((E + 511) / 512) + 4095) / 4096 * 4096;
    P = (E + chunk - 1) / chunk;
  }
  const int nIter = chunk >> 8;

  // workspace carve-up (256B-aligned slabs)
  char* p = (char*)d_ws;
  auto alloc = [&](size_t bytes) -> char* {
    char* q = p;
    p += (bytes + 255) & ~(size_t)255;
    return q;
  };
  int* flag = (int*)alloc(256);
  // slabA: sort scratch (dead after fine_k) aliased with y1 (live after)
  size_t sortBytes = (size_t)E * 4 + (size_t)E * 2 + (size_t)B * P * 8 +
                     (size_t)B * 8 + (size_t)(B + 1) * 8 + 4096;
  size_t y1Bytes = (size_t)n * 256;
  char* slabA = alloc(sortBytes > y1Bytes ? sortBytes : y1Bytes);
  uint* ebuf_d = (uint*)slabA;                              // E*4
  ushort* ebuf_s = (ushort*)(ebuf_d + E);                   // E*2
  int* gh_d = (int*)(ebuf_s + ((E + 1) & ~1));              // B*P*4
  int* gh_s = gh_d + B * P;                                 // B*P*4
  int* btot = gh_s + B * P;                                 // 2B
  int* bb_d = btot + 2 * B;                                 // B+1
  int* bb_s = bb_d + (B + 1);                               // B+1
  ushort* y1 = (ushort*)slabA;                              // n*128 bf16
  // persistent slabs
  ushort* wf1 = (ushort*)alloc(16384 * 2);
  ushort* wf2 = (ushort*)alloc(16384 * 2);
  float* ns = (float*)alloc((size_t)n * 4);
  float* nd = (float*)alloc((size_t)n * 4);
  int* row_off = (int*)alloc((size_t)(n + 1) * 4);
  int* csr = (int*)alloc((size_t)E * 4);
  uint* xb = (uint*)alloc((size_t)n * 256);                 // pre-scaled bf16 x
  const int fast = ((size_t)(p - (char*)d_ws) <= ws_size) ? 1 : 0;

  const int TB = 256;
  const int gAg = (n + 63) / 64;

  detect_k<<<1, 64, 0, stream>>>((const uint*)feat, flag);
  wswz<<<16, TB, 0, stream>>>(W1, W2, wf1, wf2, flag);
  part_hist<<<P, TB, 0, stream>>>(src, dst, gh_d, gh_s, B, P, nIter, E);
  part_scan<<<2 * B, TB, 0, stream>>>(gh_d, gh_s, btot, B, P);
  bucket_scan<<<1, 64, 0, stream>>>(btot, bb_d, bb_s, B);
  part_scat<<<P, TB, 0, stream>>>(src, dst, gh_d, gh_s, bb_d, bb_s,
                                  ebuf_d, ebuf_s, B, P, nIter, E);
  fine_k<<<2 * B, TB, 0, stream>>>(ebuf_d, ebuf_s, bb_d, bb_s, row_off, csr,
                                   ns, nd, feat, xb, flag, fast, B, n, E);

  // layer 1: gather prescaled x, GEMM W1, relu, pre-scale by ns -> y1 (bf16)
  aggemm<<<gAg, TB, 0, stream>>>(fast ? (const void*)xb : feat, row_off, csr,
                                 nd, ns, wf1, b1, (void*)y1,
                                 fast, 1, 0, flag, n);
  // layer 2: gather y1, GEMM W2 -> d_out (f32 unless bf16 inputs)
  aggemm<<<gAg, TB, 0, stream>>>((const void*)y1, row_off, csr, nd, ns, wf2,
                                 b2, d_out, 1, 0, 1, flag, n);
}